// Round 8
// baseline (33816.428 us; speedup 1.0000x reference)
//
#include <hip/hip_runtime.h>
#include <math.h>

#define TT 8192
#define DD 128
#define HH 1024
#define RINGN 64           // ring slots; A-B lag bound 48 via amortized checks
#define NA 64              // layer-0 workgroups
#define NB 128             // layer-1 (+decoder) workgroups
#define NWG (NA + NB)

// d_ws layout (bytes):
//   [0)     b_cons u32[128]  B's consumption epoch of h0 (A's ring reuse)
//   [1024)  a_fA u32[64]     A-step flags, replica polled by A-group
//   [1536)  a_fB u32[64]     replica polled by B-group
//   [2048)  b_fB u32[128]    B-step flags (B self-loop)
//   [4096)            h0A ull[RINGN][HH]   (value f32 | epoch u32) pairs
//   [4096+0.5MB)      h0B
//   [4096+1.0MB)      h1B
// Protocol: producers store pairs (relaxed 8B agent atomics), DRAIN
// (s_waitcnt vmcnt(0)), s_barrier, then per-WG flag store. Flag visible =>
// pairs visible, so the consumer's epoch-validate passes first try (retry
// kept as a correctness net). Detect = one wave polling 64/128 flags.
// Staging is stride-1 into LDS. Decoder folded into B (uses the h1(t-1)
// already staged each step; computed off-critical-path after the flag).

typedef unsigned long long ull;

__device__ __forceinline__ ull ldpair(const ull* p) {
  return __hip_atomic_load(p, __ATOMIC_RELAXED, __HIP_MEMORY_SCOPE_AGENT);
}
__device__ __forceinline__ void stpair(ull* p, float v, unsigned e) {
  ull u = ((ull)e << 32) | (ull)__float_as_uint(v);
  __hip_atomic_store(p, u, __ATOMIC_RELAXED, __HIP_MEMORY_SCOPE_AGENT);
}
__device__ __forceinline__ unsigned ldflag(const unsigned* p) {
  return __hip_atomic_load(p, __ATOMIC_RELAXED, __HIP_MEMORY_SCOPE_AGENT);
}
__device__ __forceinline__ void stflag(unsigned* p, unsigned v) {
  __hip_atomic_store(p, v, __ATOMIC_RELAXED, __HIP_MEMORY_SCOPE_AGENT);
}
__device__ __forceinline__ float sigm(float x) { return 1.0f / (1.0f + expf(-x)); }
__device__ __forceinline__ float softplusf(float x) {
  return x > 0.0f ? x + log1pf(expf(-x)) : log1pf(expf(x));
}

#define DRAIN()  asm volatile("s_waitcnt vmcnt(0)" ::: "memory")
#define CFENCE() asm volatile("" ::: "memory")

#define FMA16(W)                                                      \
  a0 = fmaf(W[0][4*i+0], h4.x, a0); a0 = fmaf(W[0][4*i+1], h4.y, a0); \
  a0 = fmaf(W[0][4*i+2], h4.z, a0); a0 = fmaf(W[0][4*i+3], h4.w, a0); \
  a1 = fmaf(W[1][4*i+0], h4.x, a1); a1 = fmaf(W[1][4*i+1], h4.y, a1); \
  a1 = fmaf(W[1][4*i+2], h4.z, a1); a1 = fmaf(W[1][4*i+3], h4.w, a1); \
  a2 = fmaf(W[2][4*i+0], h4.x, a2); a2 = fmaf(W[2][4*i+1], h4.y, a2); \
  a2 = fmaf(W[2][4*i+2], h4.z, a2); a2 = fmaf(W[2][4*i+3], h4.w, a2); \
  a3 = fmaf(W[3][4*i+0], h4.x, a3); a3 = fmaf(W[3][4*i+1], h4.y, a3); \
  a3 = fmaf(W[3][4*i+2], h4.z, a3); a3 = fmaf(W[3][4*i+3], h4.w, a3);

__global__ void __launch_bounds__(512, 1) deepar_persistent(
    const float* __restrict__ obs,
    const float* __restrict__ Wih0, const float* __restrict__ Whh0, const float* __restrict__ b0,
    const float* __restrict__ Wih1, const float* __restrict__ Whh1, const float* __restrict__ b1,
    const float* __restrict__ Wdec, const float* __restrict__ bdec,
    float* __restrict__ out,
    unsigned* b_cons, unsigned* a_fA, unsigned* a_fB, unsigned* b_fB,
    ull* h0A, ull* h0B, ull* h1B)
{
  __shared__ __align__(16) float hx[2][2304];

  const int wg   = blockIdx.x;
  const int tid  = threadIdx.x;
  const int wid  = tid >> 6;
  const int lane = tid & 63;

  if (wg < NA) {
    //========== Group A: layer-0. 16 j's/WG; 32 lanes per j ==========
    const int rg = tid >> 5;          // 0..15 (j within WG)
    const int q  = tid & 31;          // 36-wide k-slice of [h0(1024); x(128)]
    const int j  = wg * 16 + rg;
    const int k0 = q * 36;
    float w[4][36];
    #pragma unroll
    for (int i = 0; i < 9; ++i) {
      const int kb = k0 + 4 * i;
      #pragma unroll
      for (int r = 0; r < 4; ++r) {
        const float* src = (kb < HH) ? (Whh0 + (size_t)(r * HH + j) * HH + kb)
                                     : (Wih0 + (size_t)(r * HH + j) * DD + (kb - HH));
        const float4 v = *(const float4*)src;
        w[r][4*i+0] = v.x; w[r][4*i+1] = v.y; w[r][4*i+2] = v.z; w[r][4*i+3] = v.w;
      }
    }
    float bs[4];
    #pragma unroll
    for (int r = 0; r < 4; ++r) bs[r] = b0[r * HH + j];
    float creg = 0.0f;

    for (int t = 0; t < TT; ++t) {
      float a0 = 0.f, a1 = 0.f, a2 = 0.f, a3 = 0.f;
      if (t > 0) {                     // x-part: cached loads, off critical path
        const float* obr = obs + (size_t)(t - 1) * DD;
        #pragma unroll
        for (int i = 0; i < 9; ++i) {
          const int kb = k0 + 4 * i;
          if (kb >= HH) { const float4 h4 = *(const float4*)(obr + (kb - HH)); FMA16(w) }
        }
      }
      // wave1: amortized ring-reuse backpressure (B consumed h0(t-32))
      if (wid == 1 && ((t & 15) == 0) && t >= 48) {
        const unsigned need = (unsigned)(t - 32);
        while (!__all((ldflag(&b_cons[lane]) >= need) &
                      (ldflag(&b_cons[lane + 64]) >= need))) {}
      }
      // wave0: narrow detect -- poll sibling flags
      if (wid == 0 && t > 0) {
        const unsigned tg = (unsigned)t;
        while (!__all((lane == wg) | (ldflag(&a_fA[lane]) >= tg))) {}
      }
      __builtin_amdgcn_s_barrier();
      float* Lb = hx[t & 1];
      if (t > 0) {                     // bulk read (validate passes 1st try)
        const ull* sl = h0A + (size_t)((t - 1) & (RINGN - 1)) * HH;
        const unsigned ee = (unsigned)t;
        ull u0 = ldpair(sl + tid);
        ull u1 = ldpair(sl + tid + 512);
        while ((unsigned)(u0 >> 32) != ee) u0 = ldpair(sl + tid);
        Lb[tid] = __uint_as_float((unsigned)u0);
        while ((unsigned)(u1 >> 32) != ee) u1 = ldpair(sl + tid + 512);
        Lb[tid + 512] = __uint_as_float((unsigned)u1);
      }
      __syncthreads();
      if (t > 0) {
        #pragma unroll
        for (int i = 0; i < 9; ++i) {
          const int kb = k0 + 4 * i;
          if (kb < HH) { const float4 h4 = *(const float4*)&Lb[kb]; FMA16(w) }
        }
      }
      #pragma unroll
      for (int s = 1; s < 32; s <<= 1) {
        a0 += __shfl_xor(a0, s); a1 += __shfl_xor(a1, s);
        a2 += __shfl_xor(a2, s); a3 += __shfl_xor(a3, s);
      }
      if (q == 0) {
        const float ig = sigm(a0 + bs[0]);
        const float fg = sigm(a1 + bs[1]);
        const float gg = tanhf(a2 + bs[2]);
        const float og = sigm(a3 + bs[3]);
        creg = fg * creg + ig * gg;
        const float hv = og * tanhf(creg);
        const size_t off = (size_t)(t & (RINGN - 1)) * HH + j;
        const unsigned ep = (unsigned)(t + 1);
        stpair(&h0A[off], hv, ep);
        stpair(&h0B[off], hv, ep);
      }
      DRAIN();                         // pairs at coherence point
      __builtin_amdgcn_s_barrier();    // ... for ALL waves
      CFENCE();
      if (tid == 0) { stflag(&a_fA[wg], (unsigned)(t + 1));
                      stflag(&a_fB[wg], (unsigned)(t + 1)); }
    }

  } else {
    //========== Group B: layer-1 + decoder. 8 j's/WG; 64 lanes per j ==========
    const int rg = tid >> 6;          // 0..7
    const int q  = tid & 63;          // 32-wide k-slice of [h0(t); h1(t-1)]
    const int s_ = wg - NA;
    const int j  = s_ * 8 + rg;
    const int k0 = q * 32;
    float w[4][32];
    #pragma unroll
    for (int i = 0; i < 8; ++i) {
      const int kb = k0 + 4 * i;
      #pragma unroll
      for (int r = 0; r < 4; ++r) {
        const float* src = (kb < HH) ? (Wih1 + (size_t)(r * HH + j) * HH + kb)
                                     : (Whh1 + (size_t)(r * HH + j) * HH + (kb - HH));
        const float4 v = *(const float4*)src;
        w[r][4*i+0] = v.x; w[r][4*i+1] = v.y; w[r][4*i+2] = v.z; w[r][4*i+3] = v.w;
      }
    }
    float bs[4];
    #pragma unroll
    for (int r = 0; r < 4; ++r) bs[r] = b1[r * HH + j];
    float creg = 0.0f;
    const int p0 = tid + 4 * (tid >> 5);     // h0 elem tid (padded)
    const int p1 = p0 + 576;                 // h0 elem tid+512
    const int p2 = p0 + 1152;                // h1 elem tid
    const int p3 = p2 + 576;                 // h1 elem tid+512
    const int baseB = (q < 32) ? q * 36 : 1152 + (q - 32) * 36;
    // decoder row (waves 2,3): crow = s_*2 + (wid-2)
    const int crow = s_ * 2 + (wid - 2);
    float wd[16];
    float bsd = 0.0f;
    if (wid == 2 || wid == 3) {
      #pragma unroll
      for (int i = 0; i < 4; ++i) {
        const float4 v = *(const float4*)(Wdec + (size_t)crow * HH + lane * 16 + 4 * i);
        wd[4*i+0] = v.x; wd[4*i+1] = v.y; wd[4*i+2] = v.z; wd[4*i+3] = v.w;
      }
      bsd = bdec[crow];
    }
    // h1(t-1) element m lives at Lb[1152 + m + 4*(m>>5)]; lane's 16 are contiguous
    const int dbase = 1152 + lane * 16 + 4 * ((lane * 16) >> 5);

    for (int t = 0; t <= TT; ++t) {
      // wave0: narrow detect on a_fB (h0(t)) + b_fB (h1(t-1))
      if (wid == 0) {
        const unsigned eA = (unsigned)(t + 1);
        const unsigned eB = (unsigned)t;
        for (;;) {
          int ok = 1;
          if (t < TT) ok &= (ldflag(&a_fB[lane]) >= eA);
          if (t > 0) {
            ok &= (lane == s_)        | (ldflag(&b_fB[lane])      >= eB);
            ok &= ((lane + 64) == s_) | (ldflag(&b_fB[lane + 64]) >= eB);
          }
          if (__all(ok)) break;
        }
      }
      __builtin_amdgcn_s_barrier();
      float* Lb = hx[t & 1];
      {
        const unsigned e0 = (unsigned)(t + 1);
        const unsigned e1 = (unsigned)t;   // t==0: memset pairs (0,0) match
        if (t < TT) {
          const ull* s0 = h0B + (size_t)(t & (RINGN - 1)) * HH;
          ull u0 = ldpair(s0 + tid);
          ull u1 = ldpair(s0 + tid + 512);
          while ((unsigned)(u0 >> 32) != e0) u0 = ldpair(s0 + tid);
          Lb[p0] = __uint_as_float((unsigned)u0);
          while ((unsigned)(u1 >> 32) != e0) u1 = ldpair(s0 + tid + 512);
          Lb[p1] = __uint_as_float((unsigned)u1);
        }
        const ull* s1 = h1B + (size_t)((t - 1) & (RINGN - 1)) * HH;
        ull u2 = ldpair(s1 + tid);
        ull u3 = ldpair(s1 + tid + 512);
        while ((unsigned)(u2 >> 32) != e1) u2 = ldpair(s1 + tid);
        Lb[p2] = __uint_as_float((unsigned)u2);
        while ((unsigned)(u3 >> 32) != e1) u3 = ldpair(s1 + tid + 512);
        Lb[p3] = __uint_as_float((unsigned)u3);
      }
      __syncthreads();
      if (tid == 64 && t < TT) stflag(&b_cons[s_], (unsigned)(t + 1)); // h0(t) consumed
      if (t < TT) {
        float a0 = 0.f, a1 = 0.f, a2 = 0.f, a3 = 0.f;
        #pragma unroll
        for (int i = 0; i < 8; ++i) {
          const float4 h4 = *(const float4*)&Lb[baseB + 4 * i];
          FMA16(w)
        }
        #pragma unroll
        for (int s = 1; s < 64; s <<= 1) {
          a0 += __shfl_xor(a0, s); a1 += __shfl_xor(a1, s);
          a2 += __shfl_xor(a2, s); a3 += __shfl_xor(a3, s);
        }
        if (q == 0) {
          const float ig = sigm(a0 + bs[0]);
          const float fg = sigm(a1 + bs[1]);
          const float gg = tanhf(a2 + bs[2]);
          const float og = sigm(a3 + bs[3]);
          creg = fg * creg + ig * gg;
          stpair(&h1B[(size_t)(t & (RINGN - 1)) * HH + j], og * tanhf(creg),
                 (unsigned)(t + 1));
        }
        DRAIN();
        __builtin_amdgcn_s_barrier();
        CFENCE();
        if (tid == 0) stflag(&b_fB[s_], (unsigned)(t + 1));
      }
      // decoder for step t-1 (off critical path, uses staged h1(t-1))
      if (t > 0 && (wid == 2 || wid == 3)) {
        float a = 0.f;
        #pragma unroll
        for (int i = 0; i < 4; ++i) {
          const float4 h4 = *(const float4*)&Lb[dbase + 4 * i];
          a = fmaf(wd[4*i+0], h4.x, a); a = fmaf(wd[4*i+1], h4.y, a);
          a = fmaf(wd[4*i+2], h4.z, a); a = fmaf(wd[4*i+3], h4.w, a);
        }
        #pragma unroll
        for (int s = 1; s < 64; s <<= 1) a += __shfl_xor(a, s);
        if (lane == 0) {
          const float z = a + bsd;
          if (crow < DD) out[(size_t)(t - 1) * DD + crow] = z;
          else out[(size_t)TT * DD + (size_t)(t - 1) * DD + (crow - DD)]
                 = softplusf(z) + 1e-4f;
        }
      }
    }
  }
}

extern "C" void kernel_launch(void* const* d_in, const int* in_sizes, int n_in,
                              void* d_out, int out_size, void* d_ws, size_t ws_size,
                              hipStream_t stream) {
  const float* obs  = (const float*)d_in[0];
  const float* Wih0 = (const float*)d_in[1];
  const float* Whh0 = (const float*)d_in[2];
  const float* b0   = (const float*)d_in[3];
  const float* Wih1 = (const float*)d_in[4];
  const float* Whh1 = (const float*)d_in[5];
  const float* b1   = (const float*)d_in[6];
  const float* Wdec = (const float*)d_in[7];
  const float* bdec = (const float*)d_in[8];
  float* out = (float*)d_out;

  const size_t RB = (size_t)RINGN * HH * 8;   // 512 KB per ring replica
  unsigned char* ws = (unsigned char*)d_ws;
  unsigned* b_cons = (unsigned*)(ws);
  unsigned* a_fA   = (unsigned*)(ws + 1024);
  unsigned* a_fB   = (unsigned*)(ws + 1536);
  unsigned* b_fB   = (unsigned*)(ws + 2048);
  ull* h0A = (ull*)(ws + 4096);
  ull* h0B = (ull*)(ws + 4096 + RB);
  ull* h1B = (ull*)(ws + 4096 + 2 * RB);

  // zero flags + ring replicas every call (epochs restart; replay-safe)
  hipMemsetAsync(ws, 0, 4096 + 3 * RB, stream);

  hipLaunchKernelGGL(deepar_persistent, dim3(NWG), dim3(512), 0, stream,
                     obs, Wih0, Whh0, b0, Wih1, Whh1, b1, Wdec, bdec, out,
                     b_cons, a_fA, a_fB, b_fB, h0A, h0B, h1B);
}